// Round 9
// baseline (9357.605 us; speedup 1.0000x reference)
//
#include <hip/hip_runtime.h>
#include <math.h>

#pragma clang fp contract(off)

// LTC network: B=32, T=128, IN=128, H=256, OUT=128, 5 RK4 steps/t, dt=0.01
// Round 9: target = JAX CPU fp32 (XLA) golden, exp-form logistic.
//  - matmuls (Eigen gebp): per-output ascending-k fmaf chain from 0.0;
//    x/bias added AFTER as separate unfused f32 op
//  - sigmoid = LogisticExpander: 1/(1+exp(-z)); exp = XLA llvm_ir_runtime
//    GenerateVF32Exp (Cephes): clamp [-88.3762626647949, 88.3762626647950],
//    fx = floor(fma(x, log2e, 0.5)); UNFUSED Cody-Waite (mul, sub, mul, sub);
//    FMA Horner p0..p5; y = fma(y, x^2, x); y = 1+y; scale 2^fx via
//    ((int)fx + 127) << 23 bitcast; product y*s. IEEE div.
//  - RK4 elementwise: plain unfused IEEE f32; f32 weak-typed constants
//  - ffp-contract OFF file-wide; explicit __builtin_fmaf only where XLA fuses
// Structure (race-audited): k_ltc 32 blocks x 512 thr; tid<256 = S-chain +
// elementwise for unit i; tid>=256 = A-chain. W rows 192 in VGPRs + 64-col
// transposed tail from L2.
// ws (floats): W_inT[0,32768) W_outT[32768,65536) tailT_rec[65536,81920)
// tailT_adapt[81920,98304) emb[98304,1146880) h_hist[1146880,2195456)

#define Bn 32
#define Tn 128
#define INn 128
#define Hn 256
#define OUTn 128
#define NSTEPS 5

__device__ __forceinline__ float f32clip(float x, float lo, float hi) {
  float y = (x >= lo) ? x : lo;
  y = (y <= hi) ? y : hi;
  return (x == x) ? y : x;    // NaN propagates (no NaNs occur; safety)
}

// XLA CPU GenerateVF32Exp (Cephes expf), bit-exact reconstruction.
__device__ __forceinline__ float xla_expf(float x) {
  x = fminf(x, 88.3762626647950f);         // clamp high
  x = fmaxf(x, -88.3762626647949f);        // clamp low
  float fx = floorf(__builtin_fmaf(x, 1.44269504088896341f, 0.5f)); // fused
  float tmp = __fmul_rn(0.693359375f, fx);         // unfused Cody-Waite hi
  float z  = __fmul_rn(-2.12194440e-4f, fx);       // unfused Cody-Waite lo
  float r  = __fsub_rn(x, tmp);
  r = __fsub_rn(r, z);
  float r2 = __fmul_rn(r, r);
  float y = __builtin_fmaf(r, 1.9875691500e-4f, 1.3981999507e-3f);  // MulAdd
  y = __builtin_fmaf(y, r, 8.3334519073e-3f);
  y = __builtin_fmaf(y, r, 4.1665795894e-2f);
  y = __builtin_fmaf(y, r, 1.6666665459e-1f);
  y = __builtin_fmaf(y, r, 5.0000001201e-1f);
  y = __builtin_fmaf(y, r2, r);
  y = __fadd_rn(1.0f, y);
  int m = (int)fx;                          // FPToSI (fx integral)
  float s = __int_as_float((m + 127) << 23);
  return __fmul_rn(y, s);
}

// LogisticExpander: 1 / (1 + exp(-z))
__device__ __forceinline__ float xla_sigmoid(float zin) {
  float e = xla_expf(-zin);
  return 1.0f / __fadd_rn(1.0f, e);        // IEEE f32 div
}

__global__ __launch_bounds__(256) void k_prep(const float* __restrict__ W_in,
                                              const float* __restrict__ W_out,
                                              const float* __restrict__ W_rec,
                                              const float* __restrict__ W_adapt,
                                              float* __restrict__ W_inT,
                                              float* __restrict__ W_outT,
                                              float* __restrict__ tailT_rec,
                                              float* __restrict__ tailT_adapt) {
  int idx = blockIdx.x * 256 + threadIdx.x;     // 384*256 = 98304
  if (idx < 32768) {            // W_in [256][128] -> W_inT[j][h]
    int h = idx >> 7, j = idx & 127;
    W_inT[j * Hn + h] = W_in[idx];
  } else if (idx < 65536) {     // W_out [128][256] -> W_outT[i][o]
    int k = idx - 32768; int o = k >> 8, i = k & 255;
    W_outT[i * OUTn + o] = W_out[k];
  } else if (idx < 81920) {     // W_rec[:,192:256] -> tailT_rec[jj][i]
    int k = idx - 65536; int i = k >> 6, jj = k & 63;
    tailT_rec[jj * Hn + i] = W_rec[i * Hn + 192 + jj];
  } else {                      // W_adapt[:,192:256] -> tailT_adapt[jj][i]
    int k = idx - 81920; int i = k >> 6, jj = k & 63;
    tailT_adapt[jj * Hn + i] = W_adapt[i * Hn + 192 + jj];
  }
}

// emb[b,t,h] = (ascending-i fmaf chain, Eigen) x[b,t,:].W_in[h,:], then + b_in
__global__ __launch_bounds__(256) void k_embed(const float* __restrict__ xin,
                                               const float* __restrict__ W_inT,
                                               const float* __restrict__ b_in,
                                               float* __restrict__ emb) {
  __shared__ float xs[INn];
  int bt = blockIdx.x, h = threadIdx.x;
  if (h < INn) xs[h] = xin[bt * INn + h];
  __syncthreads();
  float d = 0.f;
  #pragma unroll
  for (int j = 0; j < INn; ++j)
    d = __builtin_fmaf(xs[j], W_inT[j * Hn + h], d);  // Eigen gebp chain
  emb[bt * Hn + h] = __fadd_rn(d, b_in[h]);           // + b_in separate op
}

__global__ __launch_bounds__(512) void k_ltc(const float* __restrict__ W_rec,
                                             const float* __restrict__ W_adapt,
                                             const float* __restrict__ tau,
                                             const float* __restrict__ tailT_rec,
                                             const float* __restrict__ tailT_adapt,
                                             const float* __restrict__ emb,
                                             float* __restrict__ h_hist) {
  const int b = blockIdx.x;
  const int tid = threadIdx.x;
  const int role = tid >> 8;     // 0: S-chain (W_rec) + elementwise; 1: A-chain
  const int i = tid & 255;

  __shared__ float h_lds[Hn];
  __shared__ float partA[Hn];

  const float* Wsrc = role ? W_adapt : W_rec;
  float w[192];
  #pragma unroll
  for (int m = 0; m < 192; ++m) w[m] = Wsrc[i * Hn + m];   // one-time row load
  const float* tailT = role ? tailT_adapt : tailT_rec;
  const float tau_i = tau[i];
  const float C_DT6 = (float)(0.01 / 6.0);   // f32(DT/6.0), weak-scalar cast
  float h = 0.f, hcur = 0.f, acc = 0.f;
  if (role == 0) h_lds[i] = 0.f;
  __syncthreads();

  #pragma unroll 1
  for (int t = 0; t < Tn; ++t) {
    const float x = (role == 0) ? emb[(b * Tn + t) * Hn + i] : 0.f;
    #pragma unroll 1
    for (int s = 0; s < NSTEPS; ++s) {
      #pragma unroll 1
      for (int st = 0; st < 4; ++st) {
        // dot: ascending-j fmaf chain from 0 (Eigen gebp per-element chain)
        float d = 0.f;
        #pragma unroll
        for (int j = 0; j < 192; ++j)
          d = __builtin_fmaf(h_lds[j], w[j], d);
        #pragma unroll
        for (int j = 192; j < 256; ++j)
          d = __builtin_fmaf(h_lds[j], tailT[(j - 192) * Hn + i], d);
        if (role == 1) partA[i] = d;
        __syncthreads();
        if (role == 0) {
          float S = __fadd_rn(x, d);              // S = x + h@W_rec.T
          float z = __fadd_rn(S, partA[i]);       // S + h@W_adapt.T
          float sig = xla_sigmoid(z);             // 1/(1+exp(-z)), Cephes exp
          float tvc = f32clip(__fmul_rn(tau_i, sig), 1e-6f, 1e6f);
          float kk = __fsub_rn(S, hcur) / tvc;    // separate sub, IEEE div
          if (st == 0) {
            acc = kk;
            hcur = __fadd_rn(h, __fmul_rn(0.005f, kk));
          } else if (st == 1) {
            acc = __fadd_rn(acc, __fmul_rn(2.f, kk));
            hcur = __fadd_rn(h, __fmul_rn(0.005f, kk));
          } else if (st == 2) {
            acc = __fadd_rn(acc, __fmul_rn(2.f, kk));
            hcur = __fadd_rn(h, __fmul_rn(0.01f, kk));
          } else {
            acc = __fadd_rn(acc, kk);
            float dl = f32clip(__fmul_rn(acc, C_DT6), -1e6f, 1e6f);
            h = __fadd_rn(h, dl);
            hcur = h;
          }
          h_lds[i] = hcur;
        }
        __syncthreads();
      }
    }
    if (role == 0) h_hist[(b * Tn + t) * Hn + i] = h;
  }
}

// out[b,t,o] = (ascending fmaf chain) h.W_out[o,:], then + b_out[o]
__global__ __launch_bounds__(128) void k_out(const float* __restrict__ h_hist,
                                             const float* __restrict__ W_outT,
                                             const float* __restrict__ b_out,
                                             float* __restrict__ outp) {
  __shared__ float hs[Hn];
  int bt = blockIdx.x, o = threadIdx.x;
  hs[o] = h_hist[bt * Hn + o];
  hs[o + 128] = h_hist[bt * Hn + o + 128];
  __syncthreads();
  float d = 0.f;
  #pragma unroll
  for (int j = 0; j < Hn; ++j)
    d = __builtin_fmaf(hs[j], W_outT[j * OUTn + o], d);
  outp[bt * OUTn + o] = __fadd_rn(d, b_out[o]);
}

extern "C" void kernel_launch(void* const* d_in, const int* in_sizes, int n_in,
                              void* d_out, int out_size, void* d_ws, size_t ws_size,
                              hipStream_t stream) {
  const float* x       = (const float*)d_in[0];
  const float* W_in    = (const float*)d_in[1];
  const float* b_in    = (const float*)d_in[2];
  const float* W_rec   = (const float*)d_in[3];
  const float* W_adapt = (const float*)d_in[4];
  const float* W_out   = (const float*)d_in[5];
  const float* b_out   = (const float*)d_in[6];
  const float* tau     = (const float*)d_in[7];
  float* outp = (float*)d_out;
  float* ws = (float*)d_ws;

  float* W_inT      = ws;                 // 32768
  float* W_outT     = ws + 32768;         // 32768
  float* tailT_rec  = ws + 65536;         // 16384
  float* tailT_adapt= ws + 81920;         // 16384
  float* emb        = ws + 98304;         // 1048576
  float* h_hist     = ws + 1146880;       // 1048576

  (void)in_sizes; (void)n_in; (void)out_size; (void)ws_size;

  k_prep<<<384, 256, 0, stream>>>(W_in, W_out, W_rec, W_adapt,
                                  W_inT, W_outT, tailT_rec, tailT_adapt);
  k_embed<<<Bn * Tn, 256, 0, stream>>>(x, W_inT, b_in, emb);
  k_ltc<<<Bn, 512, 0, stream>>>(W_rec, W_adapt, tau, tailT_rec, tailT_adapt,
                                emb, h_hist);
  k_out<<<Bn * Tn, 128, 0, stream>>>(h_hist, W_outT, b_out, outp);
}

// Round 10
// 9132.894 us; speedup vs baseline: 1.0246x; 1.0246x over previous
//
#include <hip/hip_runtime.h>
#include <math.h>

#pragma clang fp contract(off)

// LTC network: B=32, T=128, IN=128, H=256, OUT=128, 5 RK4 steps/t, dt=0.01
// Round 10: same bit-exact arithmetic as R9 (PASSED, absmax 0.0), perf fixes:
//  - __launch_bounds__(512, 2): 256-VGPR cap so w[192] stays in registers
//    (R9: VGPR_Count=128 -> w[] spilled to scratch -> 2048 VMEM/CU/stage)
//  - h broadcasts via float4 ds_read_b128 (64 DS instr/thread/stage vs 256);
//    per-element fmaf order unchanged -> bit-identical
//  - h_lds aligned 16
// Numerics (DO NOT TOUCH — bit-exact vs XLA-CPU golden):
//  - dots: ascending-k __builtin_fmaf chain from 0.0; x/bias added after,
//    unfused; sigmoid = 1/(1+CephesExp(-z)) per GenerateVF32Exp; unfused
//    RK4 elementwise; fp contract off file-wide.

#define Bn 32
#define Tn 128
#define INn 128
#define Hn 256
#define OUTn 128
#define NSTEPS 5

__device__ __forceinline__ float f32clip(float x, float lo, float hi) {
  float y = (x >= lo) ? x : lo;
  y = (y <= hi) ? y : hi;
  return (x == x) ? y : x;    // NaN propagates (safety; none occur)
}

// XLA CPU GenerateVF32Exp (Cephes expf), bit-exact reconstruction.
__device__ __forceinline__ float xla_expf(float x) {
  x = fminf(x, 88.3762626647950f);         // clamp high
  x = fmaxf(x, -88.3762626647949f);        // clamp low
  float fx = floorf(__builtin_fmaf(x, 1.44269504088896341f, 0.5f)); // fused
  float tmp = __fmul_rn(0.693359375f, fx);         // unfused Cody-Waite hi
  float z  = __fmul_rn(-2.12194440e-4f, fx);       // unfused Cody-Waite lo
  float r  = __fsub_rn(x, tmp);
  r = __fsub_rn(r, z);
  float r2 = __fmul_rn(r, r);
  float y = __builtin_fmaf(r, 1.9875691500e-4f, 1.3981999507e-3f);  // MulAdd
  y = __builtin_fmaf(y, r, 8.3334519073e-3f);
  y = __builtin_fmaf(y, r, 4.1665795894e-2f);
  y = __builtin_fmaf(y, r, 1.6666665459e-1f);
  y = __builtin_fmaf(y, r, 5.0000001201e-1f);
  y = __builtin_fmaf(y, r2, r);
  y = __fadd_rn(1.0f, y);
  int m = (int)fx;                          // FPToSI (fx integral)
  float s = __int_as_float((m + 127) << 23);
  return __fmul_rn(y, s);
}

// LogisticExpander: 1 / (1 + exp(-z))
__device__ __forceinline__ float xla_sigmoid(float zin) {
  float e = xla_expf(-zin);
  return 1.0f / __fadd_rn(1.0f, e);        // IEEE f32 div
}

__global__ __launch_bounds__(256) void k_prep(const float* __restrict__ W_in,
                                              const float* __restrict__ W_out,
                                              const float* __restrict__ W_rec,
                                              const float* __restrict__ W_adapt,
                                              float* __restrict__ W_inT,
                                              float* __restrict__ W_outT,
                                              float* __restrict__ tailT_rec,
                                              float* __restrict__ tailT_adapt) {
  int idx = blockIdx.x * 256 + threadIdx.x;     // 384*256 = 98304
  if (idx < 32768) {            // W_in [256][128] -> W_inT[j][h]
    int h = idx >> 7, j = idx & 127;
    W_inT[j * Hn + h] = W_in[idx];
  } else if (idx < 65536) {     // W_out [128][256] -> W_outT[i][o]
    int k = idx - 32768; int o = k >> 8, i = k & 255;
    W_outT[i * OUTn + o] = W_out[k];
  } else if (idx < 81920) {     // W_rec[:,192:256] -> tailT_rec[jj][i]
    int k = idx - 65536; int i = k >> 6, jj = k & 63;
    tailT_rec[jj * Hn + i] = W_rec[i * Hn + 192 + jj];
  } else {                      // W_adapt[:,192:256] -> tailT_adapt[jj][i]
    int k = idx - 81920; int i = k >> 6, jj = k & 63;
    tailT_adapt[jj * Hn + i] = W_adapt[i * Hn + 192 + jj];
  }
}

// emb[b,t,h] = (ascending-i fmaf chain, Eigen) x[b,t,:].W_in[h,:], then + b_in
__global__ __launch_bounds__(256) void k_embed(const float* __restrict__ xin,
                                               const float* __restrict__ W_inT,
                                               const float* __restrict__ b_in,
                                               float* __restrict__ emb) {
  __shared__ float xs[INn];
  int bt = blockIdx.x, h = threadIdx.x;
  if (h < INn) xs[h] = xin[bt * INn + h];
  __syncthreads();
  float d = 0.f;
  #pragma unroll
  for (int j = 0; j < INn; ++j)
    d = __builtin_fmaf(xs[j], W_inT[j * Hn + h], d);  // Eigen gebp chain
  emb[bt * Hn + h] = __fadd_rn(d, b_in[h]);           // + b_in separate op
}

__global__ __launch_bounds__(512, 2) void k_ltc(const float* __restrict__ W_rec,
                                                const float* __restrict__ W_adapt,
                                                const float* __restrict__ tau,
                                                const float* __restrict__ tailT_rec,
                                                const float* __restrict__ tailT_adapt,
                                                const float* __restrict__ emb,
                                                float* __restrict__ h_hist) {
  const int b = blockIdx.x;
  const int tid = threadIdx.x;
  const int role = tid >> 8;     // 0: S-chain (W_rec) + elementwise; 1: A-chain
  const int i = tid & 255;

  __shared__ __align__(16) float h_lds[Hn];
  __shared__ float partA[Hn];

  const float* Wsrc = role ? W_adapt : W_rec;
  float w[192];
  #pragma unroll
  for (int m = 0; m < 192; ++m) w[m] = Wsrc[i * Hn + m];   // one-time row load
  const float* tailT = role ? tailT_adapt : tailT_rec;
  const float tau_i = tau[i];
  const float C_DT6 = (float)(0.01 / 6.0);   // f32(DT/6.0), weak-scalar cast
  float h = 0.f, hcur = 0.f, acc = 0.f;
  if (role == 0) h_lds[i] = 0.f;
  __syncthreads();

  #pragma unroll 1
  for (int t = 0; t < Tn; ++t) {
    const float x = (role == 0) ? emb[(b * Tn + t) * Hn + i] : 0.f;
    #pragma unroll 1
    for (int s = 0; s < NSTEPS; ++s) {
      #pragma unroll 1
      for (int st = 0; st < 4; ++st) {
        // dot: ascending-j fmaf chain from 0 (Eigen gebp per-element chain).
        // h loaded as float4 broadcasts (b128); per-element order unchanged.
        float d = 0.f;
        const float4* h4 = reinterpret_cast<const float4*>(h_lds);
        #pragma unroll
        for (int j4 = 0; j4 < 48; ++j4) {           // j = 0..191 from VGPRs
          const float4 hv = h4[j4];
          d = __builtin_fmaf(hv.x, w[4*j4+0], d);
          d = __builtin_fmaf(hv.y, w[4*j4+1], d);
          d = __builtin_fmaf(hv.z, w[4*j4+2], d);
          d = __builtin_fmaf(hv.w, w[4*j4+3], d);
        }
        #pragma unroll
        for (int j4 = 48; j4 < 64; ++j4) {          // j = 192..255 from L2
          const float4 hv = h4[j4];
          const int jj = 4*j4 - 192;
          d = __builtin_fmaf(hv.x, tailT[(jj+0) * Hn + i], d);
          d = __builtin_fmaf(hv.y, tailT[(jj+1) * Hn + i], d);
          d = __builtin_fmaf(hv.z, tailT[(jj+2) * Hn + i], d);
          d = __builtin_fmaf(hv.w, tailT[(jj+3) * Hn + i], d);
        }
        if (role == 1) partA[i] = d;
        __syncthreads();
        if (role == 0) {
          float S = __fadd_rn(x, d);              // S = x + h@W_rec.T
          float z = __fadd_rn(S, partA[i]);       // S + h@W_adapt.T
          float sig = xla_sigmoid(z);             // 1/(1+exp(-z)), Cephes exp
          float tvc = f32clip(__fmul_rn(tau_i, sig), 1e-6f, 1e6f);
          float kk = __fsub_rn(S, hcur) / tvc;    // separate sub, IEEE div
          if (st == 0) {
            acc = kk;
            hcur = __fadd_rn(h, __fmul_rn(0.005f, kk));
          } else if (st == 1) {
            acc = __fadd_rn(acc, __fmul_rn(2.f, kk));
            hcur = __fadd_rn(h, __fmul_rn(0.005f, kk));
          } else if (st == 2) {
            acc = __fadd_rn(acc, __fmul_rn(2.f, kk));
            hcur = __fadd_rn(h, __fmul_rn(0.01f, kk));
          } else {
            acc = __fadd_rn(acc, kk);
            float dl = f32clip(__fmul_rn(acc, C_DT6), -1e6f, 1e6f);
            h = __fadd_rn(h, dl);
            hcur = h;
          }
          h_lds[i] = hcur;
        }
        __syncthreads();
      }
    }
    if (role == 0) h_hist[(b * Tn + t) * Hn + i] = h;
  }
}

// out[b,t,o] = (ascending fmaf chain) h.W_out[o,:], then + b_out[o]
__global__ __launch_bounds__(128) void k_out(const float* __restrict__ h_hist,
                                             const float* __restrict__ W_outT,
                                             const float* __restrict__ b_out,
                                             float* __restrict__ outp) {
  __shared__ float hs[Hn];
  int bt = blockIdx.x, o = threadIdx.x;
  hs[o] = h_hist[bt * Hn + o];
  hs[o + 128] = h_hist[bt * Hn + o + 128];
  __syncthreads();
  float d = 0.f;
  #pragma unroll
  for (int j = 0; j < Hn; ++j)
    d = __builtin_fmaf(hs[j], W_outT[j * OUTn + o], d);
  outp[bt * OUTn + o] = __fadd_rn(d, b_out[o]);
}

extern "C" void kernel_launch(void* const* d_in, const int* in_sizes, int n_in,
                              void* d_out, int out_size, void* d_ws, size_t ws_size,
                              hipStream_t stream) {
  const float* x       = (const float*)d_in[0];
  const float* W_in    = (const float*)d_in[1];
  const float* b_in    = (const float*)d_in[2];
  const float* W_rec   = (const float*)d_in[3];
  const float* W_adapt = (const float*)d_in[4];
  const float* W_out   = (const float*)d_in[5];
  const float* b_out   = (const float*)d_in[6];
  const float* tau     = (const float*)d_in[7];
  float* outp = (float*)d_out;
  float* ws = (float*)d_ws;

  float* W_inT      = ws;                 // 32768
  float* W_outT     = ws + 32768;         // 32768
  float* tailT_rec  = ws + 65536;         // 16384
  float* tailT_adapt= ws + 81920;         // 16384
  float* emb        = ws + 98304;         // 1048576
  float* h_hist     = ws + 1146880;       // 1048576

  (void)in_sizes; (void)n_in; (void)out_size; (void)ws_size;

  k_prep<<<384, 256, 0, stream>>>(W_in, W_out, W_rec, W_adapt,
                                  W_inT, W_outT, tailT_rec, tailT_adapt);
  k_embed<<<Bn * Tn, 256, 0, stream>>>(x, W_inT, b_in, emb);
  k_ltc<<<Bn, 512, 0, stream>>>(W_rec, W_adapt, tau, tailT_rec, tailT_adapt,
                                emb, h_hist);
  k_out<<<Bn * Tn, 128, 0, stream>>>(h_hist, W_outT, b_out, outp);
}

// Round 11
// 8429.016 us; speedup vs baseline: 1.1102x; 1.0835x over previous
//
#include <hip/hip_runtime.h>
#include <math.h>

#pragma clang fp contract(off)

// LTC network: B=32, T=128, IN=128, H=256, OUT=128, 5 RK4 steps/t, dt=0.01
// Round 11: same bit-exact arithmetic as R9/R10 (absmax 0.0). Perf:
//  - __launch_bounds__(512, 1): register budget >=256 under either
//    interpretation of arg2 (R10's (512,2) left cap at 128 -> w[] in scratch,
//    ~7000cy/stage of L2 scratch reloads = the measured bottleneck)
//  - asm-pin w[0..191] after load: opaque asm defs can't be rematerialized
//    from memory -> true VGPR residency (~230 live <= 256 budget)
//  - k_prep builds full 256x256 transposes; register load is coalesced
//    (w[m] = WT[m*256+i]); streamed tail = rows 192..255 of same transpose.
//    Identical values, identical fmaf order -> bit-identical output.
// Numerics (DO NOT TOUCH — bit-exact vs XLA-CPU golden):
//  dots: ascending-k __builtin_fmaf chain from 0.0; x/bias added after,
//  unfused; sigmoid = 1/(1+CephesExp(-z)) per GenerateVF32Exp; unfused RK4
//  elementwise; fp contract off file-wide.

#define Bn 32
#define Tn 128
#define INn 128
#define Hn 256
#define OUTn 128
#define NSTEPS 5

__device__ __forceinline__ float f32clip(float x, float lo, float hi) {
  float y = (x >= lo) ? x : lo;
  y = (y <= hi) ? y : hi;
  return (x == x) ? y : x;    // NaN propagates (safety; none occur)
}

// XLA CPU GenerateVF32Exp (Cephes expf), bit-exact reconstruction.
__device__ __forceinline__ float xla_expf(float x) {
  x = fminf(x, 88.3762626647950f);         // clamp high
  x = fmaxf(x, -88.3762626647949f);        // clamp low
  float fx = floorf(__builtin_fmaf(x, 1.44269504088896341f, 0.5f)); // fused
  float tmp = __fmul_rn(0.693359375f, fx);         // unfused Cody-Waite hi
  float z  = __fmul_rn(-2.12194440e-4f, fx);       // unfused Cody-Waite lo
  float r  = __fsub_rn(x, tmp);
  r = __fsub_rn(r, z);
  float r2 = __fmul_rn(r, r);
  float y = __builtin_fmaf(r, 1.9875691500e-4f, 1.3981999507e-3f);  // MulAdd
  y = __builtin_fmaf(y, r, 8.3334519073e-3f);
  y = __builtin_fmaf(y, r, 4.1665795894e-2f);
  y = __builtin_fmaf(y, r, 1.6666665459e-1f);
  y = __builtin_fmaf(y, r, 5.0000001201e-1f);
  y = __builtin_fmaf(y, r2, r);
  y = __fadd_rn(1.0f, y);
  int m = (int)fx;                          // FPToSI (fx integral)
  float s = __int_as_float((m + 127) << 23);
  return __fmul_rn(y, s);
}

// LogisticExpander: 1 / (1 + exp(-z))
__device__ __forceinline__ float xla_sigmoid(float zin) {
  float e = xla_expf(-zin);
  return 1.0f / __fadd_rn(1.0f, e);        // IEEE f32 div
}

__global__ __launch_bounds__(256) void k_prep(const float* __restrict__ W_in,
                                              const float* __restrict__ W_out,
                                              const float* __restrict__ W_rec,
                                              const float* __restrict__ W_adapt,
                                              float* __restrict__ W_inT,
                                              float* __restrict__ W_outT,
                                              float* __restrict__ W_recT,
                                              float* __restrict__ W_adaptT) {
  int idx = blockIdx.x * 256 + threadIdx.x;     // 768*256 = 196608
  if (idx < 32768) {            // W_in [256][128] -> W_inT[j][h]
    int h = idx >> 7, j = idx & 127;
    W_inT[j * Hn + h] = W_in[idx];
  } else if (idx < 65536) {     // W_out [128][256] -> W_outT[i][o]
    int k = idx - 32768; int o = k >> 8, i = k & 255;
    W_outT[i * OUTn + o] = W_out[k];
  } else if (idx < 131072) {    // W_rec [256][256] -> W_recT[c][r]
    int k = idx - 65536; int r = k >> 8, c = k & 255;
    W_recT[c * Hn + r] = W_rec[k];
  } else {                      // W_adapt -> W_adaptT[c][r]
    int k = idx - 131072; int r = k >> 8, c = k & 255;
    W_adaptT[c * Hn + r] = W_adapt[k];
  }
}

// emb[b,t,h] = (ascending-i fmaf chain, Eigen) x[b,t,:].W_in[h,:], then + b_in
__global__ __launch_bounds__(256) void k_embed(const float* __restrict__ xin,
                                               const float* __restrict__ W_inT,
                                               const float* __restrict__ b_in,
                                               float* __restrict__ emb) {
  __shared__ float xs[INn];
  int bt = blockIdx.x, h = threadIdx.x;
  if (h < INn) xs[h] = xin[bt * INn + h];
  __syncthreads();
  float d = 0.f;
  #pragma unroll
  for (int j = 0; j < INn; ++j)
    d = __builtin_fmaf(xs[j], W_inT[j * Hn + h], d);  // Eigen gebp chain
  emb[bt * Hn + h] = __fadd_rn(d, b_in[h]);           // + b_in separate op
}

__global__ __launch_bounds__(512, 1) void k_ltc(const float* __restrict__ W_recT,
                                                const float* __restrict__ W_adaptT,
                                                const float* __restrict__ tau,
                                                const float* __restrict__ emb,
                                                float* __restrict__ h_hist) {
  const int b = blockIdx.x;
  const int tid = threadIdx.x;
  const int role = tid >> 8;     // 0: S-chain (W_rec) + elementwise; 1: A-chain
  const int i = tid & 255;

  __shared__ __align__(16) float h_lds[Hn];
  __shared__ float partA[Hn];

  const float* WT = role ? W_adaptT : W_recT;
  float w[192];
  #pragma unroll
  for (int m = 0; m < 192; ++m) w[m] = WT[m * Hn + i];   // coalesced one-time
  #pragma unroll
  for (int m = 0; m < 192; ++m) asm volatile("" : "+v"(w[m]));  // pin in VGPRs
  const float* tailT = WT + 192 * Hn;       // rows 192..255 of the transpose
  const float tau_i = tau[i];
  const float C_DT6 = (float)(0.01 / 6.0);  // f32(DT/6.0), weak-scalar cast
  float h = 0.f, hcur = 0.f, acc = 0.f;
  if (role == 0) h_lds[i] = 0.f;
  __syncthreads();

  #pragma unroll 1
  for (int t = 0; t < Tn; ++t) {
    const float x = (role == 0) ? emb[(b * Tn + t) * Hn + i] : 0.f;
    #pragma unroll 1
    for (int s = 0; s < NSTEPS; ++s) {
      #pragma unroll 1
      for (int st = 0; st < 4; ++st) {
        // dot: ascending-j fmaf chain from 0 (Eigen gebp per-element chain).
        // h loaded as float4 broadcasts (b128); per-element order unchanged.
        float d = 0.f;
        const float4* h4 = reinterpret_cast<const float4*>(h_lds);
        #pragma unroll
        for (int j4 = 0; j4 < 48; ++j4) {           // j = 0..191 from VGPRs
          const float4 hv = h4[j4];
          d = __builtin_fmaf(hv.x, w[4*j4+0], d);
          d = __builtin_fmaf(hv.y, w[4*j4+1], d);
          d = __builtin_fmaf(hv.z, w[4*j4+2], d);
          d = __builtin_fmaf(hv.w, w[4*j4+3], d);
        }
        #pragma unroll
        for (int j4 = 48; j4 < 64; ++j4) {          // j = 192..255 from L2
          const float4 hv = h4[j4];
          const int jj = 4*j4 - 192;
          d = __builtin_fmaf(hv.x, tailT[(jj+0) * Hn + i], d);
          d = __builtin_fmaf(hv.y, tailT[(jj+1) * Hn + i], d);
          d = __builtin_fmaf(hv.z, tailT[(jj+2) * Hn + i], d);
          d = __builtin_fmaf(hv.w, tailT[(jj+3) * Hn + i], d);
        }
        if (role == 1) partA[i] = d;
        __syncthreads();
        if (role == 0) {
          float S = __fadd_rn(x, d);              // S = x + h@W_rec.T
          float z = __fadd_rn(S, partA[i]);       // S + h@W_adapt.T
          float sig = xla_sigmoid(z);             // 1/(1+exp(-z)), Cephes exp
          float tvc = f32clip(__fmul_rn(tau_i, sig), 1e-6f, 1e6f);
          float kk = __fsub_rn(S, hcur) / tvc;    // separate sub, IEEE div
          if (st == 0) {
            acc = kk;
            hcur = __fadd_rn(h, __fmul_rn(0.005f, kk));
          } else if (st == 1) {
            acc = __fadd_rn(acc, __fmul_rn(2.f, kk));
            hcur = __fadd_rn(h, __fmul_rn(0.005f, kk));
          } else if (st == 2) {
            acc = __fadd_rn(acc, __fmul_rn(2.f, kk));
            hcur = __fadd_rn(h, __fmul_rn(0.01f, kk));
          } else {
            acc = __fadd_rn(acc, kk);
            float dl = f32clip(__fmul_rn(acc, C_DT6), -1e6f, 1e6f);
            h = __fadd_rn(h, dl);
            hcur = h;
          }
          h_lds[i] = hcur;
        }
        __syncthreads();
      }
    }
    if (role == 0) h_hist[(b * Tn + t) * Hn + i] = h;
  }
}

// out[b,t,o] = (ascending fmaf chain) h.W_out[o,:], then + b_out[o]
__global__ __launch_bounds__(128) void k_out(const float* __restrict__ h_hist,
                                             const float* __restrict__ W_outT,
                                             const float* __restrict__ b_out,
                                             float* __restrict__ outp) {
  __shared__ float hs[Hn];
  int bt = blockIdx.x, o = threadIdx.x;
  hs[o] = h_hist[bt * Hn + o];
  hs[o + 128] = h_hist[bt * Hn + o + 128];
  __syncthreads();
  float d = 0.f;
  #pragma unroll
  for (int j = 0; j < Hn; ++j)
    d = __builtin_fmaf(hs[j], W_outT[j * OUTn + o], d);
  outp[bt * OUTn + o] = __fadd_rn(d, b_out[o]);
}

extern "C" void kernel_launch(void* const* d_in, const int* in_sizes, int n_in,
                              void* d_out, int out_size, void* d_ws, size_t ws_size,
                              hipStream_t stream) {
  const float* x       = (const float*)d_in[0];
  const float* W_in    = (const float*)d_in[1];
  const float* b_in    = (const float*)d_in[2];
  const float* W_rec   = (const float*)d_in[3];
  const float* W_adapt = (const float*)d_in[4];
  const float* W_out   = (const float*)d_in[5];
  const float* b_out   = (const float*)d_in[6];
  const float* tau     = (const float*)d_in[7];
  float* outp = (float*)d_out;
  float* ws = (float*)d_ws;

  float* W_inT   = ws;                 // 32768
  float* W_outT  = ws + 32768;         // 32768
  float* W_recT  = ws + 65536;         // 65536
  float* W_adaptT= ws + 131072;        // 65536
  float* emb     = ws + 196608;        // 1048576
  float* h_hist  = ws + 1245184;       // 1048576  (end 2293760 floats ~9.2MB)

  (void)in_sizes; (void)n_in; (void)out_size; (void)ws_size;

  k_prep<<<768, 256, 0, stream>>>(W_in, W_out, W_rec, W_adapt,
                                  W_inT, W_outT, W_recT, W_adaptT);
  k_embed<<<Bn * Tn, 256, 0, stream>>>(x, W_inT, b_in, emb);
  k_ltc<<<Bn, 512, 0, stream>>>(W_recT, W_adaptT, tau, emb, h_hist);
  k_out<<<Bn * Tn, 128, 0, stream>>>(h_hist, W_outT, b_out, outp);
}